// Round 9
// baseline (6101.834 us; speedup 1.0000x reference)
//
#include <hip/hip_runtime.h>

// LSTM T=16384, B=32, H=96. 32 blocks x 512 thr (8 waves, 2/SIMD -- R20 frame;
// R21's 12 waves regressed: tail is per-wave redundant, +50% VALU issue).
// R20 budget @2.4GHz: 672cy = 350 MFMA burst (18/SIMD x 19.4cy) + 120 ds_read
// + ~120 VALU tail + ~80 write/barrier. VALU pipe idle during the burst.
// R22 (this): K-SPLIT ACROSS PIPES. MFMA keeps k in [0,64): 3 tiles x 2 kt =
// 6 MFMA/wave = 12/SIMD (233cy). VALU computes k in [64,96) as 16 chained
// v_dot2_f32_f16 per lane for its OWN (cell,gate) row -- 64cy/SIMD issue,
// co-issued with the MFMA burst (separate pipes, m114). gx seeds the dot
// chain; tail gains one add (pre = acc_sel + vpart). The h[64..96) slice is a
// lane-uniform LDS read (broadcast, conflict-free). Same f16 products + f32
// accumulation -> absmax unchanged.
// Unchanged (HW-verified): A = h replicated rows, B = weights cols (tile t
// col c -> cell 4t+(c>>2), gate c&3), te = min(h16,2) mirror for h16=3,
// quad DPP tail, e_k prefold, scaled-domain c, 513-row slot-shifted history,
// one barrier/step, bulk fc flush per 512-step window.

constexpr int HH   = 96;
constexpr int BB   = 32;
constexpr int TT   = 16384;
constexpr int TH   = 512;   // 8 waves, 2 per SIMD
constexpr int NS   = 512;   // h history window
constexpr int ROWP = 104;   // halves per hist row: 208 B, 16B-aligned

typedef _Float16 f16x8 __attribute__((ext_vector_type(8)));
typedef _Float16 f16x2 __attribute__((ext_vector_type(2)));
typedef float    f32x4 __attribute__((ext_vector_type(4)));

__device__ __forceinline__ float dot2_f16(f16x2 a, f16x2 b, float c) {
    float d;
    int ai = __builtin_bit_cast(int, a);
    int bi = __builtin_bit_cast(int, b);
    asm("v_dot2_f32_f16 %0, %1, %2, %3" : "=v"(d) : "v"(ai), "v"(bi), "v"(c));
    return d;
}

template <int CTRL>
__device__ __forceinline__ float dpp_bcast(float v) {
    int r = __builtin_amdgcn_mov_dpp(__builtin_bit_cast(int, v), CTRL, 0xF, 0xF, true);
    return __builtin_bit_cast(float, r);
}
constexpr int DPP_B1 = 0x55;
constexpr int DPP_B2 = 0xAA;
constexpr int DPP_B3 = 0xFF;

#define LOG2E 1.44269504f

__attribute__((amdgpu_flat_work_group_size(TH, TH)))
__global__ void lstm_kernel(const float* __restrict__ x,
                            const float* __restrict__ w_ih,
                            const float* __restrict__ w_hh,
                            const float* __restrict__ b_ih,
                            const float* __restrict__ b_hh,
                            const float* __restrict__ fc_w,
                            const float* __restrict__ fc_b,
                            float* __restrict__ out) {
    __shared__ __align__(16) _Float16 hist[(NS + 1) * ROWP];  // ~104 KB
    __shared__ __align__(16) float xs[NS];                    // 2 KB x window
    __shared__ float fcw_s[HH];

    const int tid = threadIdx.x;
    const int b   = blockIdx.x;
    const int wv  = tid >> 6;   // wave 0..7, owns cells [12wv, 12wv+12)
    const int l   = tid & 63;
    const int h16 = l >> 4;     // k-group 0..3; tail tile = min(h16,2)
    const int rIn = l & 15;     // col within tile
    const int s   = rIn & 3;    // gate 0..3 (quad lane)
    const int q   = rIn >> 2;   // cell-sub within tile
    const int te  = (h16 == 3) ? 2 : h16;    // tail tile (h16=3 mirrors 2)
    const int j   = 12 * wv + 4 * te + q;    // this lane's cell 0..95

    const float ek_s = (s == 2) ? (-2.0f * LOG2E) : (-LOG2E);

    // MFMA B fragments (k in [0,64)), e_k-prescaled. Tile t col rIn holds W
    // row (gate s, cell 12wv+4t+q); lane's k slice = kt*32 + 8*h16 + e.
    f16x8 Bw[3][2];
#pragma unroll
    for (int t = 0; t < 3; ++t) {
        const float* wrow = w_hh + (s * HH + 12 * wv + 4 * t + q) * HH;
#pragma unroll
        for (int kt = 0; kt < 2; ++kt) {
            const float* wr = wrow + kt * 32 + 8 * h16;
            f16x8 v;
#pragma unroll
            for (int e = 0; e < 8; ++e) v[e] = (_Float16)(wr[e] * ek_s);
            Bw[t][kt] = v;
        }
    }
#pragma unroll
    for (int t = 0; t < 3; ++t)
#pragma unroll
        for (int kt = 0; kt < 2; ++kt) asm volatile("" : "+v"(Bw[t][kt]));

    // VALU weights: this lane's own row (gate s, cell j), k in [64,96).
    f16x2 Wl[16];
    {
        const float* wr = w_hh + (s * HH + j) * HH + 64;
#pragma unroll
        for (int m = 0; m < 16; ++m)
            Wl[m] = f16x2{(_Float16)(wr[2 * m] * ek_s),
                          (_Float16)(wr[2 * m + 1] * ek_s)};
    }
#pragma unroll
    for (int m = 0; m < 16; ++m) asm volatile("" : "+v"(Wl[m]));

    const float wih2  = w_ih[s * HH + j] * ek_s;
    const float bias2 = (b_ih[s * HH + j] + b_hh[s * HH + j]) * ek_s;
    const float a_mul = (s == 2) ? (-4.0f * LOG2E) : 1.0f;
    const float a_add = (s == 2) ? (2.0f * LOG2E) : 0.0f;
    const bool  te1 = (h16 == 1), te2 = (h16 >= 2);

    const float fcb = fc_b[0];
    float c = 0.0f;   // scaled domain: c' = -2*log2e * c_true

    for (int i = tid; i < HH; i += TH) fcw_s[i] = fc_w[i];

    // Bulk fc projection for window [t0, t0+NS): h(t0+i) is in hist row i+1.
    auto flush = [&](int t0) {
        for (int i = tid; i < NS; i += TH) {
            const uint2* hr = (const uint2*)(hist + (i + 1) * ROWP);
            float a = 0.0f;
#pragma unroll
            for (int m = 0; m < 24; ++m) {
                uint2 u = hr[m];
                f16x2 p0 = __builtin_bit_cast(f16x2, u.x);
                f16x2 p1 = __builtin_bit_cast(f16x2, u.y);
                a = fmaf((float)p0.x, fcw_s[4 * m + 0], a);
                a = fmaf((float)p0.y, fcw_s[4 * m + 1], a);
                a = fmaf((float)p1.x, fcw_s[4 * m + 2], a);
                a = fmaf((float)p1.y, fcw_s[4 * m + 3], a);
            }
            out[(t0 + i) * BB + b] = a + fcb + xs[i];
        }
    };

    const _Float16* rd_p;  // h(t-1) MFMA k-slice base (8*h16); +4 rows/block
    const _Float16* rd_u;  // h(t-1) VALU slice base (+64, lane-uniform)
    _Float16*       wr_p;  // h(t) cell slot base

    auto step = [&](float gx, const int ofs) {   // ofs: constant element offset
        const uint4* p  = (const uint4*)(rd_p + ofs);
        const uint4* pu = (const uint4*)(rd_u + ofs);
        uint4 u0 = p[0], u1 = p[4];              // kt stride: 32 halves = 64B
        uint4 v0 = pu[0], v1 = pu[1], v2 = pu[2], v3 = pu[3];  // h[64..96)
        const f16x8 a0 = __builtin_bit_cast(f16x8, u0);
        const f16x8 a1 = __builtin_bit_cast(f16x8, u1);
        f16x2 hv[16];
        {
            uint4 vv[4] = {v0, v1, v2, v3};
#pragma unroll
            for (int r = 0; r < 4; ++r) {
                hv[4 * r + 0] = __builtin_bit_cast(f16x2, vv[r].x);
                hv[4 * r + 1] = __builtin_bit_cast(f16x2, vv[r].y);
                hv[4 * r + 2] = __builtin_bit_cast(f16x2, vv[r].z);
                hv[4 * r + 3] = __builtin_bit_cast(f16x2, vv[r].w);
            }
        }

        // MFMA pipe: k in [0,64), 3 tile-chains x 2, C zero-init (movs hide
        // under ds_read latency).
        f32x4 acc[3] = {{0.f, 0.f, 0.f, 0.f}, {0.f, 0.f, 0.f, 0.f},
                        {0.f, 0.f, 0.f, 0.f}};
#pragma unroll
        for (int t = 0; t < 3; ++t)
            acc[t] = __builtin_amdgcn_mfma_f32_16x16x32_f16(a0, Bw[t][0], acc[t], 0, 0, 0);
#pragma unroll
        for (int t = 0; t < 3; ++t)
            acc[t] = __builtin_amdgcn_mfma_f32_16x16x32_f16(a1, Bw[t][1], acc[t], 0, 0, 0);

        // VALU pipe (co-issued with MFMA): k in [64,96), gx seeds chain a.
        float ea = gx, eb = 0.0f;
#pragma unroll
        for (int m = 0; m < 8; ++m) {
            ea = dot2_f16(Wl[2 * m + 0], hv[2 * m + 0], ea);
            eb = dot2_f16(Wl[2 * m + 1], hv[2 * m + 1], eb);
        }
        const float vpart = ea + eb;

        // Rows are replicas -> reg 0 always; 2-cndmask tile select by te.
        float pre = te1 ? acc[1][0] : acc[0][0];
        pre       = te2 ? acc[2][0] : pre;
        pre += vpart;

        const float act =
            fmaf(__builtin_amdgcn_rcpf(1.0f + __builtin_amdgcn_exp2f(pre)),
                 a_mul, a_add);
        const float fv = dpp_bcast<DPP_B1>(act);
        const float gv = dpp_bcast<DPP_B2>(act);   // already -2k-scaled
        const float ov = dpp_bcast<DPP_B3>(act);
        c = fmaf(fv, c, act * gv);                 // scaled domain
        const float rt = __builtin_amdgcn_rcpf(1.0f + __builtin_amdgcn_exp2f(c));
        const float h  = fmaf(ov + ov, rt, -ov);   // o * tanh(c_true)
        if (s == 0 && h16 < 3) *(wr_p + ofs) = (_Float16)h;
        __syncthreads();
    };

    for (int w = 0; w < TT / NS; ++w) {
        const int t0 = w * NS;
        if (w == 0) {
            if (tid < 48) ((uint32_t*)hist)[tid] = 0u;  // row 0 = h(-1) = 0
        } else {
            flush(t0 - NS);                              // old xs + rows 1..512
            if (tid < 48)                                // row 512 -> row 0
                ((uint32_t*)hist)[tid] = ((const uint32_t*)(hist + NS * ROWP))[tid];
        }
        __syncthreads();
        for (int i = tid; i < NS; i += TH) xs[i] = x[(t0 + i) * BB + b];
        __syncthreads();

        rd_p = hist + 8 * h16;
        rd_u = hist + 64;
        wr_p = hist + ROWP + j;
        for (int tt = 0; tt < NS; tt += 4) {
            const float4 xq = *(const float4*)(xs + tt);  // broadcast
            const float gx0 = fmaf(xq.x, wih2, bias2);    // off-chain
            const float gx1 = fmaf(xq.y, wih2, bias2);
            const float gx2 = fmaf(xq.z, wih2, bias2);
            const float gx3 = fmaf(xq.w, wih2, bias2);
            step(gx0, 0 * ROWP);
            step(gx1, 1 * ROWP);
            step(gx2, 2 * ROWP);
            step(gx3, 3 * ROWP);
            rd_p += 4 * ROWP;
            rd_u += 4 * ROWP;
            wr_p += 4 * ROWP;
        }
    }
    flush(TT - NS);   // last window (loop ended with a barrier)
}

extern "C" void kernel_launch(void* const* d_in, const int* in_sizes, int n_in,
                              void* d_out, int out_size, void* d_ws, size_t ws_size,
                              hipStream_t stream) {
    const float* x    = (const float*)d_in[0];
    const float* w_ih = (const float*)d_in[1];
    const float* w_hh = (const float*)d_in[2];
    const float* b_ih = (const float*)d_in[3];
    const float* b_hh = (const float*)d_in[4];
    const float* fc_w = (const float*)d_in[5];
    const float* fc_b = (const float*)d_in[6];
    float* out = (float*)d_out;

    lstm_kernel<<<dim3(BB), dim3(TH), 0, stream>>>(x, w_ih, w_hh, b_ih, b_hh,
                                                   fc_w, fc_b, out);
}